// Round 7
// baseline (324.329 us; speedup 1.0000x reference)
//
#include <hip/hip_runtime.h>
#include <hip/hip_bf16.h>

#define B_  16
#define S_  4096
#define DIN 512
#define DH  512

typedef _Float16 f16x8 __attribute__((ext_vector_type(8)));
typedef float    f32x4 __attribute__((ext_vector_type(4)));

// ---------------- ws layout (bytes) ----------------
// W16     : [DH][DIN] fp16      @ 0        (524288)
// addv    : [B_][DH]  f32       @ 524288   (32768)   = input@W_in.T + b_in + b_ctx
// scores  : [B_][S_]  f32       @ 557056   (262144)  raw (mask applied downstream)
// wsum    : [B_][DIN] f32       @ 819200   (32768)   zeroed in prep
// maskflag: int                 @ 851968   (4)
// partials: [256]     float2    @ 852224   (2048)    per (b,chunk) {mx, expsum}

__device__ __forceinline__ float fast_tanh(float x) {
    float e = __expf(2.f * x);
    return 1.f - 2.f * __builtin_amdgcn_rcpf(e + 1.f);
}

__device__ __forceinline__ int mask_at(const void* mask, int isByte, int idx) {
    return isByte ? (int)((const unsigned char*)mask)[idx]
                  : ((const int*)mask)[idx];
}

// ---------------- prep ----------------
// blocks 0..255   : W_ctx fp32->fp16
// blocks 256..767 : addv matvec, 16 h per block (16 lanes per h)
// block  768      : mask dtype detect
// block  769      : zero wsum
__global__ void prep_kernel(const float* __restrict__ input,
                            const float* __restrict__ W_in,
                            const float* __restrict__ b_in,
                            const float* __restrict__ W_ctx,
                            const float* __restrict__ b_ctx,
                            const void*  __restrict__ mask,
                            _Float16* __restrict__ W16,
                            float* __restrict__ addv,
                            float* __restrict__ wsum,
                            int* __restrict__ maskflag) {
    int blk = blockIdx.x;
    int tid = threadIdx.x;
    if (blk < 256) {
        int base = blk * 1024 + tid * 4;
        float4 wv = *(const float4*)(W_ctx + base);
        union { _Float16 f[4]; ushort4 u; } cv;
        cv.f[0] = (_Float16)wv.x; cv.f[1] = (_Float16)wv.y;
        cv.f[2] = (_Float16)wv.z; cv.f[3] = (_Float16)wv.w;
        *(ushort4*)(W16 + base) = cv.u;
    } else if (blk < 768) {
        int t = blk - 256;           // 0..511 : 32 blocks per batch row
        int b  = t >> 5;
        int h0 = (t & 31) * 16;
        __shared__ float inrow[DIN];
        inrow[tid]       = input[b * DIN + tid];
        inrow[tid + 256] = input[b * DIN + tid + 256];
        __syncthreads();
        int h  = h0 + (tid >> 4);
        int ks = (tid & 15) * 32;
        const float* wr = W_in + (size_t)h * DIN + ks;
        float acc = 0.f;
#pragma unroll
        for (int k = 0; k < 32; k += 4) {
            float4 w4 = *(const float4*)(wr + k);
            acc += w4.x * inrow[ks + k] + w4.y * inrow[ks + k + 1]
                 + w4.z * inrow[ks + k + 2] + w4.w * inrow[ks + k + 3];
        }
#pragma unroll
        for (int o = 1; o < 16; o <<= 1) acc += __shfl_xor(acc, o, 16);
        if ((tid & 15) == 0) addv[b * DH + h] = acc + b_in[h] + b_ctx[h];
    } else if (blk == 768) {
        // int32 bools are 0/1 -> upper 3 bytes of each word are 0
        const uint4* m4 = (const uint4*)mask;
        unsigned int orw = 0;
#pragma unroll
        for (int it = 0; it < 16; ++it) {
            uint4 w = m4[it * 256 + tid];
            orw |= (w.x | w.y | w.z | w.w);
        }
        int found = ((orw & 0xFFFFFF00u) != 0) ? 1 : 0;
        __shared__ int f;
        if (tid == 0) f = 0;
        __syncthreads();
        if (found) atomicOr(&f, 1);
        __syncthreads();
        if (tid == 0) maskflag[0] = f;
    } else {
#pragma unroll
        for (int it = 0; it < 32; ++it)
            wsum[it * 256 + tid] = 0.f;
    }
}

// ---------------- score: streaming GEMM + tanh.v reduce ----------------
// Grid 256 = (b, 256-row s-stream), 1 block/CU. 512 thr = 8 waves; wave owns
// n = wave*64..+64 (4 n-tiles), all 4 m-tiles of the current 64-row sub-iter.
// Context streams ONCE: global fp32 -> VGPR cvt -> tiled LDS slots (2x64KB
// dbuf); slot (jm,kc) = 1KB, lane-linear (conflict-free b128 r/w). W16
// (L2-resident) streams into regs per kc, double-buffered. 3 barriers per
// sub-iter, each with a full kc-loop (~2.5k cyc) of slack for in-flight loads.
__global__ __launch_bounds__(512, 2)
void score_kernel(const float* __restrict__ context,
                  const _Float16* __restrict__ W16,
                  const float* __restrict__ addv,
                  const float* __restrict__ v,
                  float* __restrict__ scores) {
    __shared__ _Float16 Abuf[2][32768];   // 2 x 64KB: 64 slots x 512 halves
    __shared__ float avS[DH];
    __shared__ float vvS[DH];
    __shared__ float scoreAcc[64];

    const int tid  = threadIdx.x;
    const int wave = tid >> 6;
    const int lane = tid & 63;
    const int l15  = lane & 15;
    const int q    = lane >> 4;
    const int b     = blockIdx.x >> 4;
    const int sbase = (blockIdx.x & 15) * 256;
    const int n0w   = wave * 64;

    if (tid < DH) { avS[tid] = addv[b * DH + tid]; vvS[tid] = v[tid]; }
    avS[tid < DH ? tid : tid] = avS[tid < DH ? tid : tid];  // no-op keep
    {   // 512 threads, DH=512: one each (the above wrote all; guard was moot)
    }

    // B row base pointers (W16 L2-hot), per n-tile
    const _Float16* bp[4];
#pragma unroll
    for (int jn = 0; jn < 4; ++jn)
        bp[jn] = W16 + (size_t)(n0w + jn * 16 + l15) * DIN + q * 8;

    // ---- staging helpers: wave stages slots s = wave*8+u, jm=s>>4, kc=s&15 ----
    float4 La[8], Lb[8];
#define ISSUE_LOADS(si_)                                                       \
    {                                                                          \
        _Pragma("unroll")                                                      \
        for (int u = 0; u < 8; ++u) {                                          \
            int s = wave * 8 + u;                                              \
            int row_g = sbase + (si_) * 64 + ((s >> 4) << 4) + l15;            \
            const float* g = context + ((size_t)b * S_ + row_g) * DIN +        \
                             ((s & 15) << 5) + q * 8;                          \
            La[u] = *(const float4*)g;                                         \
            Lb[u] = *(const float4*)(g + 4);                                   \
        }                                                                      \
    }
#define CVT_WRITE(buf_)                                                        \
    {                                                                          \
        _Pragma("unroll")                                                      \
        for (int u = 0; u < 8; ++u) {                                          \
            int s = wave * 8 + u;                                              \
            f16x8 t;                                                           \
            t[0] = (_Float16)La[u].x; t[1] = (_Float16)La[u].y;                \
            t[2] = (_Float16)La[u].z; t[3] = (_Float16)La[u].w;                \
            t[4] = (_Float16)Lb[u].x; t[5] = (_Float16)Lb[u].y;                \
            t[6] = (_Float16)Lb[u].z; t[7] = (_Float16)Lb[u].w;                \
            *(f16x8*)&Abuf[buf_][s * 512 + lane * 8] = t;                      \
        }                                                                      \
    }

    // prologue: stage sub-iter 0 into buf 0
    ISSUE_LOADS(0);
    CVT_WRITE(0);
    __syncthreads();

    for (int si = 0; si < 4; ++si) {
        const int buf = si & 1;
        // issue next sub-iter's global loads (land during the kc loop)
        if (si + 1 < 4) ISSUE_LOADS(si + 1);

        f32x4 acc[4][4];
#pragma unroll
        for (int jm = 0; jm < 4; ++jm)
#pragma unroll
            for (int jn = 0; jn < 4; ++jn) acc[jm][jn] = (f32x4){0.f,0.f,0.f,0.f};

        // preload kc=0 frags
        f16x8 afr[2][4], bfr[2][4];
#pragma unroll
        for (int jm = 0; jm < 4; ++jm)
            afr[0][jm] = *(const f16x8*)&Abuf[buf][jm * 8192 + lane * 8];
#pragma unroll
        for (int jn = 0; jn < 4; ++jn)
            bfr[0][jn] = *(const f16x8*)bp[jn];

#pragma unroll
        for (int kc = 0; kc < 16; ++kc) {
            int cur = kc & 1, nxt = cur ^ 1;
            if (kc < 15) {
#pragma unroll
                for (int jm = 0; jm < 4; ++jm)
                    afr[nxt][jm] = *(const f16x8*)
                        &Abuf[buf][jm * 8192 + (kc + 1) * 512 + lane * 8];
#pragma unroll
                for (int jn = 0; jn < 4; ++jn)
                    bfr[nxt][jn] = *(const f16x8*)(bp[jn] + (kc + 1) * 32);
            }
#pragma unroll
            for (int jm = 0; jm < 4; ++jm)
#pragma unroll
                for (int jn = 0; jn < 4; ++jn)
                    acc[jm][jn] = __builtin_amdgcn_mfma_f32_16x16x32_f16(
                        afr[cur][jm], bfr[cur][jn], acc[jm][jn], 0, 0, 0);
        }

        // stage next sub-iter into other buffer (loads have landed by now)
        if (si + 1 < 4) CVT_WRITE(buf ^ 1);

        // ---- epilogue: rowsum over this wave's 64 n, combine across waves ----
        if (tid < 64) scoreAcc[tid] = 0.f;
        __syncthreads();
#pragma unroll
        for (int jm = 0; jm < 4; ++jm) {
            float rs[4] = {0.f, 0.f, 0.f, 0.f};
#pragma unroll
            for (int jn = 0; jn < 4; ++jn) {
                int n = n0w + jn * 16 + l15;
                float av = avS[n];
                float vv = vvS[n];
#pragma unroll
                for (int r = 0; r < 4; ++r)
                    rs[r] += vv * fast_tanh(acc[jm][jn][r] + av);
            }
#pragma unroll
            for (int r = 0; r < 4; ++r) {
                float s = rs[r];
                s += __shfl_xor(s, 1, 16);
                s += __shfl_xor(s, 2, 16);
                s += __shfl_xor(s, 4, 16);
                s += __shfl_xor(s, 8, 16);
                if (l15 == 0)
                    atomicAdd(&scoreAcc[jm * 16 + q * 4 + r], s);
            }
        }
        __syncthreads();
        if (tid < 64)
            scores[b * S_ + sbase + si * 64 + tid] = scoreAcc[tid];
        __syncthreads();   // scoreAcc reads done + Abuf writes visible
    }
#undef ISSUE_LOADS
#undef CVT_WRITE
}

// ---------------- statsP: per (b, 256-row chunk) masked {max, expsum} ----------------
__global__ __launch_bounds__(256)
void statsP_kernel(const float* __restrict__ scores,
                   const void* __restrict__ mask,
                   const int* __restrict__ maskflag,
                   float2* __restrict__ partials) {
    __shared__ float rbuf[4];
    int b  = blockIdx.x >> 4;
    int c0 = (blockIdx.x & 15) * 256;
    int tid = threadIdx.x;
    int wv = tid >> 6, ln = tid & 63;
    int isByte = maskflag[0];

    int idx = b * S_ + c0 + tid;
    float val = mask_at(mask, isByte, idx) ? -__builtin_inff() : scores[idx];

    float mx = val;
    for (int o = 1; o < 64; o <<= 1) mx = fmaxf(mx, __shfl_xor(mx, o, 64));
    if (ln == 0) rbuf[wv] = mx;
    __syncthreads();
    mx = fmaxf(fmaxf(rbuf[0], rbuf[1]), fmaxf(rbuf[2], rbuf[3]));
    __syncthreads();

    float e = __expf(val - mx);       // all -inf chunk: exp(nan)? no: val-mx = -inf - -inf = nan
    if (val == -__builtin_inff()) e = 0.f;
    float sum = e;
    for (int o = 1; o < 64; o <<= 1) sum += __shfl_xor(sum, o, 64);
    if (ln == 0) rbuf[wv] = sum;
    __syncthreads();
    if (tid == 0) {
        sum = rbuf[0] + rbuf[1] + rbuf[2] + rbuf[3];
        partials[blockIdx.x] = make_float2(mx, sum);
    }
}

// ---------------- attnwsum: combine stats + attn write + sparse weighted sum ----
__global__ __launch_bounds__(256)
void attnwsum_kernel(const float* __restrict__ scores,
                     const float* __restrict__ context,
                     const void* __restrict__ mask,
                     const int* __restrict__ maskflag,
                     const float2* __restrict__ partials,
                     float* __restrict__ attn,
                     float* __restrict__ wsum) {
    __shared__ float pmx[16], psm[16];
    __shared__ int   selIdx[256];
    __shared__ float selW[256];
    __shared__ int   selCount;

    int b  = blockIdx.x >> 4;
    int c0 = (blockIdx.x & 15) * 256;
    int tid = threadIdx.x;
    int isByte = maskflag[0];

    if (tid < 16) {
        float2 pp = partials[b * 16 + tid];
        pmx[tid] = pp.x; psm[tid] = pp.y;
    }
    if (tid == 0) selCount = 0;
    __syncthreads();
    float mx = -__builtin_inff();
#pragma unroll
    for (int i = 0; i < 16; ++i) mx = fmaxf(mx, pmx[i]);
    float sum = 0.f;
#pragma unroll
    for (int i = 0; i < 16; ++i)
        if (psm[i] > 0.f) sum += psm[i] * __expf(pmx[i] - mx);
    float inv = 1.f / sum;

    int s = c0 + tid;
    int idx = b * S_ + s;
    float sc = mask_at(mask, isByte, idx) ? -__builtin_inff() : scores[idx];
    float p = __expf(sc - mx) * inv;
    attn[idx] = p;
    if (p > 1e-9f) {
        int k = atomicAdd(&selCount, 1);
        selIdx[k] = s;
        selW[k]  = p;
    }
    __syncthreads();

    int cnt = selCount;
    if (cnt == 0) return;
    const float* cb = context + (size_t)b * S_ * DIN;
    float a00 = 0.f, a01 = 0.f, a10 = 0.f, a11 = 0.f;
    float a20 = 0.f, a21 = 0.f, a30 = 0.f, a31 = 0.f;
    int i = 0;
    for (; i + 4 <= cnt; i += 4) {
        const float* c0p = cb + (size_t)selIdx[i]     * DIN;
        const float* c1p = cb + (size_t)selIdx[i + 1] * DIN;
        const float* c2p = cb + (size_t)selIdx[i + 2] * DIN;
        const float* c3p = cb + (size_t)selIdx[i + 3] * DIN;
        float w0 = selW[i], w1 = selW[i + 1], w2 = selW[i + 2], w3 = selW[i + 3];
        a00 += w0 * c0p[tid]; a01 += w0 * c0p[tid + 256];
        a10 += w1 * c1p[tid]; a11 += w1 * c1p[tid + 256];
        a20 += w2 * c2p[tid]; a21 += w2 * c2p[tid + 256];
        a30 += w3 * c3p[tid]; a31 += w3 * c3p[tid + 256];
    }
    float acc0 = (a00 + a10) + (a20 + a30);
    float acc1 = (a01 + a11) + (a21 + a31);
    for (; i < cnt; ++i) {
        const float* cr = cb + (size_t)selIdx[i] * DIN;
        float w = selW[i];
        acc0 += w * cr[tid];
        acc1 += w * cr[tid + 256];
    }
    atomicAdd(&wsum[b * DIN + tid], acc0);
    atomicAdd(&wsum[b * DIN + tid + 256], acc1);
}

// ---------------- hidden = W_ctx @ wsum + b_ctx (16 lanes per h) ----------------
__global__ __launch_bounds__(256)
void hidden_kernel(const float* __restrict__ W_ctx,
                   const float* __restrict__ b_ctx,
                   const float* __restrict__ wsum,
                   float* __restrict__ hidden) {
    int blk = blockIdx.x;              // 512 blocks: 32 per batch row, 16 h each
    int b  = blk >> 5;
    int h0 = (blk & 31) * 16;
    int tid = threadIdx.x;
    __shared__ float wrow[DIN];
    wrow[tid]       = wsum[b * DIN + tid];
    wrow[tid + 256] = wsum[b * DIN + tid + 256];
    __syncthreads();
    int h  = h0 + (tid >> 4);
    int ks = (tid & 15) * 32;
    const float* wr = W_ctx + (size_t)h * DIN + ks;
    float acc = 0.f;
#pragma unroll
    for (int k = 0; k < 32; k += 4) {
        float4 w4 = *(const float4*)(wr + k);
        acc += w4.x * wrow[ks + k] + w4.y * wrow[ks + k + 1]
             + w4.z * wrow[ks + k + 2] + w4.w * wrow[ks + k + 3];
    }
#pragma unroll
    for (int o = 1; o < 16; o <<= 1) acc += __shfl_xor(acc, o, 16);
    if ((tid & 15) == 0) hidden[b * DH + h] = acc + b_ctx[h];
}

extern "C" void kernel_launch(void* const* d_in, const int* in_sizes, int n_in,
                              void* d_out, int out_size, void* d_ws, size_t ws_size,
                              hipStream_t stream) {
    const float* input   = (const float*)d_in[0];
    const float* context = (const float*)d_in[1];
    const void*  mask    = d_in[2];
    const float* W_in    = (const float*)d_in[3];
    const float* b_in    = (const float*)d_in[4];
    const float* W_ctx   = (const float*)d_in[5];
    const float* b_ctx   = (const float*)d_in[6];
    const float* v       = (const float*)d_in[7];

    char* ws = (char*)d_ws;
    _Float16* W16   = (_Float16*)ws;
    float* addv     = (float*)(ws + 524288);
    float* scores   = (float*)(ws + 557056);
    float* wsum     = (float*)(ws + 819200);
    int*   maskflag = (int*)(ws + 851968);
    float2* partials = (float2*)(ws + 852224);

    float* hidden = (float*)d_out;                  // [16,512]
    float* attn   = (float*)d_out + B_ * DH;        // [16,4096]

    prep_kernel<<<770, 256, 0, stream>>>(input, W_in, b_in, W_ctx, b_ctx, mask,
                                         W16, addv, wsum, maskflag);
    score_kernel<<<256, 512, 0, stream>>>(context, W16, addv, v, scores);
    statsP_kernel<<<256, 256, 0, stream>>>(scores, mask, maskflag, partials);
    attnwsum_kernel<<<256, 256, 0, stream>>>(scores, context, mask, maskflag,
                                             partials, attn, wsum);
    hidden_kernel<<<512, 256, 0, stream>>>(W_ctx, b_ctx, wsum, hidden);
}